// Round 6
// baseline (2984.350 us; speedup 1.0000x reference)
//
#include <hip/hip_runtime.h>
#include <math.h>

#ifndef __has_builtin
#define __has_builtin(x) 0
#endif

__device__ __forceinline__ float fexp2(float x) {
#if __has_builtin(__builtin_amdgcn_exp2f)
  return __builtin_amdgcn_exp2f(x);
#else
  return exp2f(x);
#endif
}
__device__ __forceinline__ float flog2(float x) {
#if __has_builtin(__builtin_amdgcn_logf)
  return __builtin_amdgcn_logf(x);
#else
  return log2f(x);
#endif
}
__device__ __forceinline__ float fsqrt_(float x) {
#if __has_builtin(__builtin_amdgcn_sqrtf)
  return __builtin_amdgcn_sqrtf(x);
#else
  return sqrtf(x);
#endif
}

constexpr int   NP    = 6144;
constexpr float LOG2E = 1.44269504088896340736f;
constexpr float EPS_F = 0.01f;
constexpr float KKc   = LOG2E / EPS_F;               // log2(e)/eps
constexpr float NKKc  = -KKc;
constexpr float LBc   = -8.72323127482750f;          // log(1/6144)
constexpr float HBc   = LBc * LOG2E;                 // log-weight, base-2
constexpr float NEL2c = -EPS_F * 0.693147180559945f; // -eps*ln(2)
constexpr float WIN   = 40.f;                        // defer/cull window (2^-40)

constexpr int RPW  = 8;            // rows per wave
constexpr int RPB  = 32;           // rows per block (4 waves)
constexpr int NRB  = NP / RPB;     // 192 row-blocks per subproblem
constexpr int NTL  = NP / 64;      // 96 column tiles of 64
constexpr int CELLS = 4096;        // 16^3 morton cells

// ---------------- sort / precompute (runs once per launch) ----------------
__device__ __forceinline__ unsigned cell_of(float v) {
  int c = (int)floorf((v + 4.0f) * 2.0f);        // cell edge 0.5 over [-4,4]
  return (unsigned)min(15, max(0, c));
}
__device__ __forceinline__ unsigned morton12(unsigned cx, unsigned cy, unsigned cz) {
  unsigned m = 0;
#pragma unroll
  for (int b = 0; b < 4; ++b)
    m |= (((cx >> b) & 1u) << (3 * b)) | (((cy >> b) & 1u) << (3 * b + 1)) |
         (((cz >> b) & 1u) << (3 * b + 2));
  return m;
}

// block 0 sorts X, block 1 sorts Y (morton counting sort), builds tile AABBs,
// zeroes half the state + hmax arrays each.
__global__ __launch_bounds__(1024) void sort_kernel(
    const float* __restrict__ xin, const float* __restrict__ yin,
    float4* __restrict__ Xp, float4* __restrict__ Xq,
    float4* __restrict__ Yp, float4* __restrict__ Yq,
    float4* __restrict__ XaLo, float4* __restrict__ XaHi,
    float4* __restrict__ YaLo, float4* __restrict__ YaHi,
    float* __restrict__ stA, float* __restrict__ hmaxA)
{
  __shared__ unsigned hist[CELLS];
  __shared__ unsigned offs[CELLS];
  __shared__ unsigned wsum[64];
  const int tid = threadIdx.x;
  const float* src = (blockIdx.x == 0) ? xin : yin;
  float4* Pp  = (blockIdx.x == 0) ? Xp : Yp;
  float4* Pq  = (blockIdx.x == 0) ? Xq : Yq;
  float4* aLo = (blockIdx.x == 0) ? XaLo : YaLo;
  float4* aHi = (blockIdx.x == 0) ? XaHi : YaHi;

  for (int i = tid; i < CELLS; i += 1024) { hist[i] = 0u; offs[i] = 0u; }
  for (int i = tid; i < 2 * NP; i += 1024) stA[blockIdx.x * 2 * NP + i] = 0.f;
  for (int i = tid; i < 2 * NRB; i += 1024) hmaxA[blockIdx.x * 2 * NRB + i] = 0.f;
  __syncthreads();

  for (int i = tid; i < NP; i += 1024) {
    float a0 = src[3*i], a1 = src[3*i+1], a2 = src[3*i+2];
    unsigned m = morton12(cell_of(a0), cell_of(a1), cell_of(a2));
    atomicAdd(&hist[m], 1u);
  }
  __syncthreads();
  if (tid < 64) {
    unsigned s = 0;
    for (int j = 0; j < 64; ++j) { unsigned v = hist[tid*64+j]; hist[tid*64+j] = s; s += v; }
    wsum[tid] = s;
  }
  __syncthreads();
  if (tid == 0) {
    unsigned s = 0;
    for (int j = 0; j < 64; ++j) { unsigned v = wsum[j]; wsum[j] = s; s += v; }
  }
  __syncthreads();
  if (tid < 64) {
    unsigned o = wsum[tid];
    for (int j = 0; j < 64; ++j) hist[tid*64+j] += o;
  }
  __syncthreads();
  for (int i = tid; i < NP; i += 1024) {
    float a0 = src[3*i], a1 = src[3*i+1], a2 = src[3*i+2];
    unsigned m = morton12(cell_of(a0), cell_of(a1), cell_of(a2));
    unsigned dst = hist[m] + atomicAdd(&offs[m], 1u);
    float an = fmaf(a0, a0, fmaf(a1, a1, a2 * a2));
    Pp[dst] = make_float4(a0, a1, a2, an);
    Pq[dst] = make_float4(-2.f*a0, -2.f*a1, -2.f*a2, an);
  }
  __syncthreads();
  const int wave = tid >> 6, lane = tid & 63;
  for (int t = wave; t < NTL; t += 16) {
    float4 p = Pp[t * 64 + lane];
    float lx = p.x, ly = p.y, lz = p.z, hx = p.x, hy = p.y, hz = p.z;
#pragma unroll
    for (int off = 32; off; off >>= 1) {
      lx = fminf(lx, __shfl_xor(lx, off)); hx = fmaxf(hx, __shfl_xor(hx, off));
      ly = fminf(ly, __shfl_xor(ly, off)); hy = fmaxf(hy, __shfl_xor(hy, off));
      lz = fminf(lz, __shfl_xor(lz, off)); hz = fmaxf(hz, __shfl_xor(hz, off));
    }
    if (lane == 0) {
      aLo[t] = make_float4(lx, ly, lz, 0.f);
      aHi[t] = make_float4(hx, hy, hz, 0.f);
    }
  }
}

// ---------------- fused culled softmin pass ----------------
// Per wave: 8 sorted rows. Tile masks (coarse) -> refined achievable bound
// (pass A) -> per-column keep test + LDS-ring stream compaction (pass B) ->
// full-wave batches of the exp2 inner loop.
__global__ __launch_bounds__(256, 4) void softmin_pass(
    const float4* __restrict__ Xp, const float4* __restrict__ Yp,
    const float4* __restrict__ Xq, const float4* __restrict__ Yq,
    const float4* __restrict__ XaLo, const float4* __restrict__ XaHi,
    const float4* __restrict__ YaLo, const float4* __restrict__ YaHi,
    const float* __restrict__ stIn, const float* __restrict__ hmaxIn,
    float* __restrict__ stOut, float* __restrict__ hmaxOut, int avg)
{
  __shared__ float4 ringQ[4][256];
  __shared__ float  ringH[4][256];
  __shared__ float  wmaxLds[4];

  const int bid  = blockIdx.x;
  const int sub  = bid & 3;
  const int rb   = bid >> 2;
  const int tid  = threadIdx.x;
  const int lane = tid & 63;
  const int wave = tid >> 6;
  const int wrow0 = rb * RPB + wave * RPW;

  const float4 *P4, *Q4, *aLo, *aHi;
  const float *hsrc, *hpair, *oldp; float* outp;
  if (sub == 0) {        // f <- softmin over Y cols, h from g
    P4 = Xp; Q4 = Yq; aLo = YaLo; aHi = YaHi;
    hsrc = stIn + NP;     hpair = hmaxIn + NRB;     oldp = stIn;          outp = stOut;
  } else if (sub == 1) { // g <- softmin over X cols, h from f
    P4 = Yp; Q4 = Xq; aLo = XaLo; aHi = XaHi;
    hsrc = stIn;          hpair = hmaxIn;           oldp = stIn + NP;     outp = stOut + NP;
  } else if (sub == 2) { // px (xx)
    P4 = Xp; Q4 = Xq; aLo = XaLo; aHi = XaHi;
    hsrc = stIn + 2*NP;   hpair = hmaxIn + 2*NRB;   oldp = stIn + 2*NP;   outp = stOut + 2*NP;
  } else {               // py (yy)
    P4 = Yp; Q4 = Yq; aLo = YaLo; aHi = YaHi;
    hsrc = stIn + 3*NP;   hpair = hmaxIn + 3*NRB;   oldp = stIn + 3*NP;   outp = stOut + 3*NP;
  }

  // ---- rows: registers + AABB + centroid/radius ----
  float pxr[RPW], pyr[RPW], pzr[RPW], pwr[RPW], mr[RPW], sr[RPW], m40r[RPW];
  float rlx, rly, rlz, rhx, rhy, rhz;
#pragma unroll
  for (int r = 0; r < RPW; ++r) {
    float4 p = P4[wrow0 + r];
    pxr[r] = p.x; pyr[r] = p.y; pzr[r] = p.z; pwr[r] = p.w;
    if (r == 0) { rlx = rhx = p.x; rly = rhy = p.y; rlz = rhz = p.z; }
    else {
      rlx = fminf(rlx, p.x); rhx = fmaxf(rhx, p.x);
      rly = fminf(rly, p.y); rhy = fmaxf(rhy, p.y);
      rlz = fminf(rlz, p.z); rhz = fmaxf(rhz, p.z);
    }
  }
  const float cx = 0.5f * (rlx + rhx), cy = 0.5f * (rly + rhy), cz = 0.5f * (rlz + rhz);
  const float cw = fmaf(cx, cx, fmaf(cy, cy, cz * cz));  // |c|^2
  float rrad = 0.f;
#pragma unroll
  for (int r = 0; r < RPW; ++r) {
    float dx = pxr[r] - cx, dy = pyr[r] - cy, dz = pzr[r] - cz;
    rrad = fmaxf(rrad, fmaf(dx, dx, fmaf(dy, dy, dz * dz)));
  }
  rrad = fsqrt_(rrad);

  // ---- coarse tile bounds (round A: tiles 0-63, round B: 64-95) ----
  float b0, b1, uc0, uc1;
  {
    auto tile_bounds = [&](int t, float& b, float& uc) {
      float4 lo = aLo[t], hi = aHi[t];
      float gx = fmaxf(fmaxf(lo.x - rhx, rlx - hi.x), 0.f);
      float gy = fmaxf(fmaxf(lo.y - rhy, rly - hi.y), 0.f);
      float gz = fmaxf(fmaxf(lo.z - rhz, rlz - hi.z), 0.f);
      float dmin = fsqrt_(fmaf(gx, gx, fmaf(gy, gy, gz * gz)));
      float fx = fmaxf(hi.x - rlx, rhx - lo.x);
      float fy = fmaxf(hi.y - rly, rhy - lo.y);
      float fz = fmaxf(hi.z - rlz, rhz - lo.z);
      float dmax = fsqrt_(fmaf(fx, fx, fmaf(fy, fy, fz * fz)));
      float hraw = fmaxf(hpair[2 * t], hpair[2 * t + 1]);
      float hh = fmaf(KKc, hraw, HBc);
      b  = fmaf(NKKc, dmin, hh);   // upper bound of any term in tile
      uc = fmaf(NKKc, dmax, hh);   // achievable lower bound (every row)
    };
    tile_bounds(lane, b0, uc0);
    int tB = (lane < 32) ? (64 + lane) : 95;
    tile_bounds(tB, b1, uc1);
    if (lane >= 32) { b1 = -INFINITY; uc1 = -INFINITY; }
  }
  float ulb = fmaxf(uc0, uc1);
#pragma unroll
  for (int off = 32; off; off >>= 1) ulb = fmaxf(ulb, __shfl_xor(ulb, off));
  const float thr0 = ulb - WIN;
  unsigned long long m0A = __ballot(b0 >= thr0);
  unsigned long long m0B = __ballot(b1 >= thr0);

  // ---- pass A: refine ulb with per-column achievable bounds ----
  float ulbl = -INFINITY;
  {
    auto refine = [&](int t) {
      int j = t * 64 + lane;
      float4 q = Q4[j];
      float hh = fmaf(KKc, hsrc[j], HBc);
      float d2c = q.w + fmaf(q.x, cx, fmaf(q.y, cy, fmaf(q.z, cz, cw)));
      float d = fsqrt_(fmaxf(d2c, 0.f));
      ulbl = fmaxf(ulbl, fmaf(NKKc, d + rrad, hh));  // every row achieves this
    };
    unsigned long long a = m0A, b = m0B;
    while (a) { int t = __ffsll(a) - 1;  a &= a - 1; refine(t); }
    while (b) { int t = 63 + __ffsll(b); b &= b - 1; refine(t); }
  }
#pragma unroll
  for (int off = 32; off; off >>= 1) ulbl = fmaxf(ulbl, __shfl_xor(ulbl, off));
  ulb = fmaxf(ulb, ulbl);
  const float thr = ulb - WIN;
  unsigned long long mA = __ballot(b0 >= thr);
  unsigned long long mB = __ballot(b1 >= thr);

#pragma unroll
  for (int r = 0; r < RPW; ++r) { mr[r] = ulb; sr[r] = 0.f; m40r[r] = ulb + WIN; }

  auto inner8 = [&](float4 q, float hh) {
#pragma unroll
    for (int r = 0; r < RPW; ++r) {
      float dot = fmaf(pxr[r], q.x, fmaf(pyr[r], q.y, fmaf(pzr[r], q.z, q.w)));
      float d2  = pwr[r] + dot;
      float c   = fsqrt_(fmaxf(d2, 1e-12f));
      float u   = fmaf(NKKc, c, hh);
      if (__any(u > m40r[r])) {
        float mn = fmaxf(mr[r], u);
        sr[r] *= fexp2(mr[r] - mn);
        mr[r] = mn; m40r[r] = mn + WIN;
      }
      sr[r] += fexp2(u - mr[r]);
    }
  };

  // ---- pass B: per-column keep test + ring compaction + batch processing ----
  int headq = 0, tailq = 0;
  {
    auto testchunk = [&](int t) {
      int j = t * 64 + lane;
      float4 q = Q4[j];
      float hh = fmaf(KKc, hsrc[j], HBc);
      float d2c = q.w + fmaf(q.x, cx, fmaf(q.y, cy, fmaf(q.z, cz, cw)));
      float d = fsqrt_(fmaxf(d2c, 0.f));
      float uhi = fmaf(NKKc, fmaxf(d - rrad, 0.f), hh); // >= any row's term
      bool keep = (uhi >= thr);
      unsigned long long k = __ballot(keep);
      if (k) {
        int my = __builtin_amdgcn_mbcnt_hi((unsigned)(k >> 32),
                 __builtin_amdgcn_mbcnt_lo((unsigned)k, 0u));
        if (keep) {
          int slot = (tailq + my) & 255;
          ringQ[wave][slot] = q;
          ringH[wave][slot] = hh;
        }
        tailq += (int)__popcll(k);
        while (tailq - headq >= 64) {
          int slot = (headq + lane) & 255;
          float4 qq = ringQ[wave][slot];
          float  hq = ringH[wave][slot];
          headq += 64;
          inner8(qq, hq);
        }
      }
    };
    unsigned long long a = mA, b = mB;
    while (a) { int t = __ffsll(a) - 1;  a &= a - 1; testchunk(t); }
    while (b) { int t = 63 + __ffsll(b); b &= b - 1; testchunk(t); }
    int rem = tailq - headq;
    if (rem > 0) {
      int slot = (headq + lane) & 255;
      float4 qq = ringQ[wave][slot];
      float  hq = ringH[wave][slot];
      if (lane >= rem) { qq = make_float4(0.f, 0.f, 0.f, 0.f); hq = -INFINITY; }
      inner8(qq, hq);
    }
  }

  // ---- merge per-lane LSE states; outputs + per-block max for next pass ----
  float wmax = -INFINITY;
#pragma unroll
  for (int r = 0; r < RPW; ++r) {
    float m = mr[r], s = sr[r];
#pragma unroll
    for (int off = 32; off; off >>= 1) {
      float mo = __shfl_xor(m, off);
      float so = __shfl_xor(s, off);
      float mn = fmaxf(m, mo);
      s = s * fexp2(m - mn) + so * fexp2(mo - mn);
      m = mn;
    }
    float val = NEL2c * (m + flog2(s));
    const int row = wrow0 + r;
    float wv = avg ? 0.5f * (oldp[row] + val) : val;
    if (lane == 0) outp[row] = wv;
    wmax = fmaxf(wmax, wv);
  }
  if (lane == 0) wmaxLds[wave] = wmax;
  __syncthreads();
  if (tid == 0)
    hmaxOut[sub * NRB + rb] =
        fmaxf(fmaxf(wmaxLds[0], wmaxLds[1]), fmaxf(wmaxLds[2], wmaxLds[3]));
}

// loss = mean(f - px) + mean(g - py)
__global__ __launch_bounds__(256) void loss_kernel(
    const float* __restrict__ st, float* __restrict__ out)
{
  double acc = 0.0;
  for (int i = threadIdx.x; i < NP; i += 256)
    acc += (double)(st[i] - st[i + 2*NP]) + (double)(st[i + NP] - st[i + 3*NP]);
  __shared__ double red[4];
#pragma unroll
  for (int off = 32; off; off >>= 1) acc += __shfl_xor(acc, off);
  const int lane = threadIdx.x & 63, wave = threadIdx.x >> 6;
  if (lane == 0) red[wave] = acc;
  __syncthreads();
  if (threadIdx.x == 0)
    out[0] = (float)((red[0] + red[1] + red[2] + red[3]) * (1.0 / NP));
}

extern "C" void kernel_launch(void* const* d_in, const int* in_sizes, int n_in,
                              void* d_out, int out_size, void* d_ws, size_t ws_size,
                              hipStream_t stream)
{
  const float* x = (const float*)d_in[0];
  const float* y = (const float*)d_in[1];
  float* out = (float*)d_out;
  float* ws  = (float*)d_ws;

  float4* Xp = (float4*)ws;                    // NP float4 each
  float4* Xq = (float4*)(ws + 4 * NP);
  float4* Yp = (float4*)(ws + 8 * NP);
  float4* Yq = (float4*)(ws + 12 * NP);
  float*  p  = ws + 16 * NP;
  float4* XaLo = (float4*)p; p += 4 * NTL;
  float4* XaHi = (float4*)p; p += 4 * NTL;
  float4* YaLo = (float4*)p; p += 4 * NTL;
  float4* YaHi = (float4*)p; p += 4 * NTL;
  float* stA = p;            p += 4 * NP;
  float* stB = p;            p += 4 * NP;
  float* hmA = p;            p += 4 * NRB;
  float* hmB = p;

  hipLaunchKernelGGL(sort_kernel, dim3(2), dim3(1024), 0, stream,
                     x, y, Xp, Xq, Yp, Yq, XaLo, XaHi, YaLo, YaHi, stA, hmA);

  float* cur = stA; float* nxt = stB;
  float* hmCur = hmA; float* hmNxt = hmB;
  for (int it = 0; it <= 32; ++it) {
    const int avg = (it < 32) ? 1 : 0;   // 32 averaged steps + 1 extrapolation
    hipLaunchKernelGGL(softmin_pass, dim3(4 * NRB), dim3(256), 0, stream,
                       Xp, Yp, Xq, Yq, XaLo, XaHi, YaLo, YaHi,
                       cur, hmCur, nxt, hmNxt, avg);
    float* t = cur; cur = nxt; nxt = t;
    t = hmCur; hmCur = hmNxt; hmNxt = t;
  }

  hipLaunchKernelGGL(loss_kernel, dim3(1), dim3(256), 0, stream, cur, out);
}

// Round 8
// 2804.486 us; speedup vs baseline: 1.0641x; 1.0641x over previous
//
#include <hip/hip_runtime.h>
#include <math.h>

#ifndef __has_builtin
#define __has_builtin(x) 0
#endif

__device__ __forceinline__ float fexp2(float x) {
#if __has_builtin(__builtin_amdgcn_exp2f)
  return __builtin_amdgcn_exp2f(x);
#else
  return exp2f(x);
#endif
}
__device__ __forceinline__ float flog2(float x) {
#if __has_builtin(__builtin_amdgcn_logf)
  return __builtin_amdgcn_logf(x);
#else
  return log2f(x);
#endif
}
__device__ __forceinline__ float fsqrt_(float x) {
#if __has_builtin(__builtin_amdgcn_sqrtf)
  return __builtin_amdgcn_sqrtf(x);
#else
  return sqrtf(x);
#endif
}

constexpr int   NP    = 6144;
constexpr float LOG2E = 1.44269504088896340736f;
constexpr float EPS_F = 0.01f;
constexpr float KKc   = LOG2E / EPS_F;               // log2(e)/eps
constexpr float NKKc  = -KKc;
constexpr float LBc   = -8.72323127482750f;          // log(1/6144)
constexpr float HBc   = LBc * LOG2E;                 // log-weight, base-2
constexpr float NEL2c = -EPS_F * 0.693147180559945f; // -eps*ln(2)
constexpr float WIN   = 40.f;                        // defer/cull window (2^-40)

constexpr int RPW  = 8;            // rows per wave
constexpr int RPB  = 32;           // rows per block (4 waves)
constexpr int NRB  = NP / RPB;     // 192 row-blocks per subproblem
constexpr int NTL  = NP / 64;      // 96 column chunks of 64
constexpr int CELLS = 4096;        // 16^3 morton cells

// ---------------- sort / precompute (runs once per launch) ----------------
// Morton sort keeps each wave's 8 rows spatially tight (small rrad), which is
// what makes the per-column triangle-inequality culling sharp.
__device__ __forceinline__ unsigned cell_of(float v) {
  int c = (int)floorf((v + 4.0f) * 2.0f);        // cell edge 0.5 over [-4,4]
  return (unsigned)min(15, max(0, c));
}
__device__ __forceinline__ unsigned morton12(unsigned cx, unsigned cy, unsigned cz) {
  unsigned m = 0;
#pragma unroll
  for (int b = 0; b < 4; ++b)
    m |= (((cx >> b) & 1u) << (3 * b)) | (((cy >> b) & 1u) << (3 * b + 1)) |
         (((cz >> b) & 1u) << (3 * b + 2));
  return m;
}

__global__ __launch_bounds__(1024) void sort_kernel(
    const float* __restrict__ xin, const float* __restrict__ yin,
    float4* __restrict__ Xp, float4* __restrict__ Xq,
    float4* __restrict__ Yp, float4* __restrict__ Yq,
    float* __restrict__ stA)
{
  __shared__ unsigned hist[CELLS];
  __shared__ unsigned offs[CELLS];
  __shared__ unsigned wsum[64];
  const int tid = threadIdx.x;
  const float* src = (blockIdx.x == 0) ? xin : yin;
  float4* Pp  = (blockIdx.x == 0) ? Xp : Yp;
  float4* Pq  = (blockIdx.x == 0) ? Xq : Yq;

  for (int i = tid; i < CELLS; i += 1024) { hist[i] = 0u; offs[i] = 0u; }
  for (int i = tid; i < 2 * NP; i += 1024) stA[blockIdx.x * 2 * NP + i] = 0.f;
  __syncthreads();

  for (int i = tid; i < NP; i += 1024) {
    float a0 = src[3*i], a1 = src[3*i+1], a2 = src[3*i+2];
    unsigned m = morton12(cell_of(a0), cell_of(a1), cell_of(a2));
    atomicAdd(&hist[m], 1u);
  }
  __syncthreads();
  if (tid < 64) {
    unsigned s = 0;
    for (int j = 0; j < 64; ++j) { unsigned v = hist[tid*64+j]; hist[tid*64+j] = s; s += v; }
    wsum[tid] = s;
  }
  __syncthreads();
  if (tid == 0) {
    unsigned s = 0;
    for (int j = 0; j < 64; ++j) { unsigned v = wsum[j]; wsum[j] = s; s += v; }
  }
  __syncthreads();
  if (tid < 64) {
    unsigned o = wsum[tid];
    for (int j = 0; j < 64; ++j) hist[tid*64+j] += o;
  }
  __syncthreads();
  for (int i = tid; i < NP; i += 1024) {
    float a0 = src[3*i], a1 = src[3*i+1], a2 = src[3*i+2];
    unsigned m = morton12(cell_of(a0), cell_of(a1), cell_of(a2));
    unsigned dst = hist[m] + atomicAdd(&offs[m], 1u);
    float an = fmaf(a0, a0, fmaf(a1, a1, a2 * a2));
    Pp[dst] = make_float4(a0, a1, a2, an);
    Pq[dst] = make_float4(-2.f*a0, -2.f*a1, -2.f*a2, an);
  }
}

// ---------------- fused culled softmin pass ----------------
// Per wave (8 sorted rows): dense pipelined pass A refines an achievable
// lower bound ulb on every row's max term; dense pass B keeps columns whose
// upper bound reaches ulb-WIN, stream-compacts them into an LDS ring, and
// processes full-wave batches of 64 through the 8-row exp2 loop.
__global__ __launch_bounds__(256, 4) void softmin_pass(
    const float4* __restrict__ Xp, const float4* __restrict__ Yp,
    const float4* __restrict__ Xq, const float4* __restrict__ Yq,
    const float* __restrict__ stIn, float* __restrict__ stOut, int avg)
{
  __shared__ float4 ringQ[4][256];
  __shared__ float  ringH[4][256];

  const int bid  = blockIdx.x;
  const int sub  = bid & 3;
  const int rb   = bid >> 2;
  const int tid  = threadIdx.x;
  const int lane = tid & 63;
  const int wave = tid >> 6;
  const int wrow0 = rb * RPB + wave * RPW;

  const float4 *P4, *Q4;
  const float *hsrc, *oldp; float* outp;
  if (sub == 0) {        // f <- softmin over Y cols, h from g
    P4 = Xp; Q4 = Yq; hsrc = stIn + NP;   oldp = stIn;        outp = stOut;
  } else if (sub == 1) { // g <- softmin over X cols, h from f
    P4 = Yp; Q4 = Xq; hsrc = stIn;        oldp = stIn + NP;   outp = stOut + NP;
  } else if (sub == 2) { // px (xx)
    P4 = Xp; Q4 = Xq; hsrc = stIn + 2*NP; oldp = stIn + 2*NP; outp = stOut + 2*NP;
  } else {               // py (yy)
    P4 = Yp; Q4 = Yq; hsrc = stIn + 3*NP; oldp = stIn + 3*NP; outp = stOut + 3*NP;
  }

  // ---- rows: registers + centroid/radius ----
  float pxr[RPW], pyr[RPW], pzr[RPW], pwr[RPW], mr[RPW], sr[RPW], m40r[RPW];
  float rlx, rly, rlz, rhx, rhy, rhz;
#pragma unroll
  for (int r = 0; r < RPW; ++r) {
    float4 p = P4[wrow0 + r];
    pxr[r] = p.x; pyr[r] = p.y; pzr[r] = p.z; pwr[r] = p.w;
    if (r == 0) { rlx = rhx = p.x; rly = rhy = p.y; rlz = rhz = p.z; }
    else {
      rlx = fminf(rlx, p.x); rhx = fmaxf(rhx, p.x);
      rly = fminf(rly, p.y); rhy = fmaxf(rhy, p.y);
      rlz = fminf(rlz, p.z); rhz = fmaxf(rhz, p.z);
    }
  }
  const float cx = 0.5f * (rlx + rhx), cy = 0.5f * (rly + rhy), cz = 0.5f * (rlz + rhz);
  const float cw = fmaf(cx, cx, fmaf(cy, cy, cz * cz));  // |c|^2
  float rrad = 0.f;
#pragma unroll
  for (int r = 0; r < RPW; ++r) {
    float dx = pxr[r] - cx, dy = pyr[r] - cy, dz = pzr[r] - cz;
    rrad = fmaxf(rrad, fmaf(dx, dx, fmaf(dy, dy, dz * dz)));
  }
  rrad = fsqrt_(rrad);

  // ---- pass A: dense refine of the achievable bound ----
  // uc_j = hh_j - KKc*(|q_j - c| + rrad) <= term_rj for every row r.
  float ulbl = -INFINITY;
#pragma unroll 4
  for (int t = 0; t < NTL; ++t) {
    int j = t * 64 + lane;
    float4 q = Q4[j];
    float hh = fmaf(KKc, hsrc[j], HBc);
    float d2c = q.w + fmaf(q.x, cx, fmaf(q.y, cy, fmaf(q.z, cz, cw)));
    float d = fsqrt_(fmaxf(d2c, 0.f));
    ulbl = fmaxf(ulbl, fmaf(NKKc, d + rrad, hh));
  }
#pragma unroll
  for (int off = 32; off; off >>= 1) ulbl = fmaxf(ulbl, __shfl_xor(ulbl, off));
  const float ulb = ulbl;
  const float thr = ulb - WIN;

#pragma unroll
  for (int r = 0; r < RPW; ++r) { mr[r] = ulb; sr[r] = 0.f; m40r[r] = ulb + WIN; }

  auto inner8 = [&](float4 q, float hh) {
#pragma unroll
    for (int r = 0; r < RPW; ++r) {
      float dot = fmaf(pxr[r], q.x, fmaf(pyr[r], q.y, fmaf(pzr[r], q.z, q.w)));
      float d2  = pwr[r] + dot;
      float c   = fsqrt_(fmaxf(d2, 1e-12f));
      float u   = fmaf(NKKc, c, hh);
      if (__any(u > m40r[r])) {          // rare: u can exceed ulb+WIN
        float mn = fmaxf(mr[r], u);
        sr[r] *= fexp2(mr[r] - mn);
        mr[r] = mn; m40r[r] = mn + WIN;
      }
      sr[r] += fexp2(u - mr[r]);
    }
  };

  // ---- pass B: dense per-column keep test + ring compaction + batches ----
  int headq = 0, tailq = 0;
#pragma unroll 2
  for (int t = 0; t < NTL; ++t) {
    int j = t * 64 + lane;
    float4 q = Q4[j];
    float hh = fmaf(KKc, hsrc[j], HBc);
    float d2c = q.w + fmaf(q.x, cx, fmaf(q.y, cy, fmaf(q.z, cz, cw)));
    float d = fsqrt_(fmaxf(d2c, 0.f));
    float uhi = fmaf(NKKc, fmaxf(d - rrad, 0.f), hh); // >= any row's term
    bool keep = (uhi >= thr);
    unsigned long long k = __ballot(keep);
    if (k) {
      int my = __builtin_amdgcn_mbcnt_hi((unsigned)(k >> 32),
               __builtin_amdgcn_mbcnt_lo((unsigned)k, 0u));
      if (keep) {
        int slot = (tailq + my) & 255;
        ringQ[wave][slot] = q;
        ringH[wave][slot] = hh;
      }
      tailq += (int)__popcll(k);
      while (tailq - headq >= 64) {
        int slot = (headq + lane) & 255;
        float4 qq = ringQ[wave][slot];
        float  hq = ringH[wave][slot];
        headq += 64;
        inner8(qq, hq);
      }
    }
  }
  {
    int rem = tailq - headq;
    if (rem > 0) {
      int slot = (headq + lane) & 255;
      float4 qq = ringQ[wave][slot];
      float  hq = ringH[wave][slot];
      if (lane >= rem) { qq = make_float4(0.f, 0.f, 0.f, 0.f); hq = -INFINITY; }
      inner8(qq, hq);
    }
  }

  // ---- merge per-lane LSE states; write outputs ----
#pragma unroll
  for (int r = 0; r < RPW; ++r) {
    float m = mr[r], s = sr[r];
#pragma unroll
    for (int off = 32; off; off >>= 1) {
      float mo = __shfl_xor(m, off);
      float so = __shfl_xor(s, off);
      float mn = fmaxf(m, mo);
      s = s * fexp2(m - mn) + so * fexp2(mo - mn);
      m = mn;
    }
    if (lane == 0) {
      float val = NEL2c * (m + flog2(s));
      const int row = wrow0 + r;
      outp[row] = avg ? 0.5f * (oldp[row] + val) : val;
    }
  }
}

// loss = mean(f - px) + mean(g - py)
__global__ __launch_bounds__(256) void loss_kernel(
    const float* __restrict__ st, float* __restrict__ out)
{
  double acc = 0.0;
  for (int i = threadIdx.x; i < NP; i += 256)
    acc += (double)(st[i] - st[i + 2*NP]) + (double)(st[i + NP] - st[i + 3*NP]);
  __shared__ double red[4];
#pragma unroll
  for (int off = 32; off; off >>= 1) acc += __shfl_xor(acc, off);
  const int lane = threadIdx.x & 63, wave = threadIdx.x >> 6;
  if (lane == 0) red[wave] = acc;
  __syncthreads();
  if (threadIdx.x == 0)
    out[0] = (float)((red[0] + red[1] + red[2] + red[3]) * (1.0 / NP));
}

extern "C" void kernel_launch(void* const* d_in, const int* in_sizes, int n_in,
                              void* d_out, int out_size, void* d_ws, size_t ws_size,
                              hipStream_t stream)
{
  const float* x = (const float*)d_in[0];
  const float* y = (const float*)d_in[1];
  float* out = (float*)d_out;
  float* ws  = (float*)d_ws;

  float4* Xp = (float4*)ws;                    // NP float4 each
  float4* Xq = (float4*)(ws + 4 * NP);
  float4* Yp = (float4*)(ws + 8 * NP);
  float4* Yq = (float4*)(ws + 12 * NP);
  float* stA = ws + 16 * NP;                   // f,g,px,py (current)
  float* stB = stA + 4 * NP;                   // f,g,px,py (next)

  hipLaunchKernelGGL(sort_kernel, dim3(2), dim3(1024), 0, stream,
                     x, y, Xp, Xq, Yp, Yq, stA);

  float* cur = stA; float* nxt = stB;
  for (int it = 0; it <= 32; ++it) {
    const int avg = (it < 32) ? 1 : 0;   // 32 averaged steps + 1 extrapolation
    hipLaunchKernelGGL(softmin_pass, dim3(4 * NRB), dim3(256), 0, stream,
                       Xp, Yp, Xq, Yq, cur, nxt, avg);
    float* t = cur; cur = nxt; nxt = t;
  }

  hipLaunchKernelGGL(loss_kernel, dim3(1), dim3(256), 0, stream, cur, out);
}

// Round 10
// 2654.798 us; speedup vs baseline: 1.1241x; 1.0564x over previous
//
#include <hip/hip_runtime.h>
#include <math.h>

#ifndef __has_builtin
#define __has_builtin(x) 0
#endif

__device__ __forceinline__ float fexp2(float x) {
#if __has_builtin(__builtin_amdgcn_exp2f)
  return __builtin_amdgcn_exp2f(x);
#else
  return exp2f(x);
#endif
}
__device__ __forceinline__ float flog2(float x) {
#if __has_builtin(__builtin_amdgcn_logf)
  return __builtin_amdgcn_logf(x);
#else
  return log2f(x);
#endif
}
__device__ __forceinline__ float fsqrt_(float x) {
#if __has_builtin(__builtin_amdgcn_sqrtf)
  return __builtin_amdgcn_sqrtf(x);
#else
  return sqrtf(x);
#endif
}

constexpr int   NP    = 6144;
constexpr float LOG2E = 1.44269504088896340736f;
constexpr float EPS_F = 0.01f;
constexpr float KKc   = LOG2E / EPS_F;               // log2(e)/eps
constexpr float NKKc  = -KKc;
constexpr float LBc   = -8.72323127482750f;          // log(1/6144)
constexpr float HBc   = LBc * LOG2E;                 // log-weight, base-2
constexpr float NEL2c = -EPS_F * 0.693147180559945f; // -eps*ln(2)
constexpr float WIN   = 24.f;   // cull/defer window: err <= 6143*2^-24 rel in S
                                // -> ~4e-6 in potentials (thr 3.3e-3). Safe.

constexpr int RPW  = 8;            // rows per wave (block = 1 wave)
constexpr int NWG  = NP / RPW;     // 768 wave-groups per subproblem
constexpr int NTL  = NP / 64;      // 96 column chunks of 64
constexpr int CELLS = 4096;        // 16^3 morton cells

// ---------------- sort / precompute (runs once per launch) ----------------
// Morton sort keeps each wave's 8 rows spatially tight (small rrad), which is
// what makes the per-column triangle-inequality culling sharp.
__device__ __forceinline__ unsigned cell_of(float v) {
  int c = (int)floorf((v + 4.0f) * 2.0f);        // cell edge 0.5 over [-4,4]
  return (unsigned)min(15, max(0, c));
}
__device__ __forceinline__ unsigned morton12(unsigned cx, unsigned cy, unsigned cz) {
  unsigned m = 0;
#pragma unroll
  for (int b = 0; b < 4; ++b)
    m |= (((cx >> b) & 1u) << (3 * b)) | (((cy >> b) & 1u) << (3 * b + 1)) |
         (((cz >> b) & 1u) << (3 * b + 2));
  return m;
}

__global__ __launch_bounds__(1024) void sort_kernel(
    const float* __restrict__ xin, const float* __restrict__ yin,
    float4* __restrict__ Xp, float4* __restrict__ Xq,
    float4* __restrict__ Yp, float4* __restrict__ Yq,
    float* __restrict__ stA)
{
  __shared__ unsigned hist[CELLS];
  __shared__ unsigned offs[CELLS];
  __shared__ unsigned wsum[64];
  const int tid = threadIdx.x;
  const float* src = (blockIdx.x == 0) ? xin : yin;
  float4* Pp  = (blockIdx.x == 0) ? Xp : Yp;
  float4* Pq  = (blockIdx.x == 0) ? Xq : Yq;

  for (int i = tid; i < CELLS; i += 1024) { hist[i] = 0u; offs[i] = 0u; }
  for (int i = tid; i < 2 * NP; i += 1024) stA[blockIdx.x * 2 * NP + i] = 0.f;
  __syncthreads();

  for (int i = tid; i < NP; i += 1024) {
    float a0 = src[3*i], a1 = src[3*i+1], a2 = src[3*i+2];
    unsigned m = morton12(cell_of(a0), cell_of(a1), cell_of(a2));
    atomicAdd(&hist[m], 1u);
  }
  __syncthreads();
  if (tid < 64) {
    unsigned s = 0;
    for (int j = 0; j < 64; ++j) { unsigned v = hist[tid*64+j]; hist[tid*64+j] = s; s += v; }
    wsum[tid] = s;
  }
  __syncthreads();
  if (tid == 0) {
    unsigned s = 0;
    for (int j = 0; j < 64; ++j) { unsigned v = wsum[j]; wsum[j] = s; s += v; }
  }
  __syncthreads();
  if (tid < 64) {
    unsigned o = wsum[tid];
    for (int j = 0; j < 64; ++j) hist[tid*64+j] += o;
  }
  __syncthreads();
  for (int i = tid; i < NP; i += 1024) {
    float a0 = src[3*i], a1 = src[3*i+1], a2 = src[3*i+2];
    unsigned m = morton12(cell_of(a0), cell_of(a1), cell_of(a2));
    unsigned dst = hist[m] + atomicAdd(&offs[m], 1u);
    float an = fmaf(a0, a0, fmaf(a1, a1, a2 * a2));
    Pp[dst] = make_float4(a0, a1, a2, an);
    Pq[dst] = make_float4(-2.f*a0, -2.f*a1, -2.f*a2, an);
  }
}

// ---------------- fused culled softmin pass ----------------
// Block = ONE wave owning 8 sorted rows (3072 independent blocks -> the HW
// scheduler load-balances; no block waits on a sibling wave). Dense pass A
// refines an achievable bound ulb; dense pass B keeps columns whose upper
// bound reaches ulb-WIN, compacts them into a 128-slot LDS ring, and drains
// full-wave batches of 64 through the 8-row exp2 loop.
__global__ __launch_bounds__(64, 8) void softmin_pass(
    const float4* __restrict__ Xp, const float4* __restrict__ Yp,
    const float4* __restrict__ Xq, const float4* __restrict__ Yq,
    const float* __restrict__ stIn, float* __restrict__ stOut, int avg)
{
  __shared__ float4 ringQ[128];
  __shared__ float  ringH[128];

  const int bid  = blockIdx.x;
  const int sub  = bid & 3;
  const int wg   = bid >> 2;
  const int lane = threadIdx.x;
  const int wrow0 = wg * RPW;

  const float4 *P4, *Q4;
  const float *hsrc, *oldp; float* outp;
  if (sub == 0) {        // f <- softmin over Y cols, h from g
    P4 = Xp; Q4 = Yq; hsrc = stIn + NP;   oldp = stIn;        outp = stOut;
  } else if (sub == 1) { // g <- softmin over X cols, h from f
    P4 = Yp; Q4 = Xq; hsrc = stIn;        oldp = stIn + NP;   outp = stOut + NP;
  } else if (sub == 2) { // px (xx)
    P4 = Xp; Q4 = Xq; hsrc = stIn + 2*NP; oldp = stIn + 2*NP; outp = stOut + 2*NP;
  } else {               // py (yy)
    P4 = Yp; Q4 = Yq; hsrc = stIn + 3*NP; oldp = stIn + 3*NP; outp = stOut + 3*NP;
  }

  // ---- rows: registers + centroid/radius ----
  float pxr[RPW], pyr[RPW], pzr[RPW], pwr[RPW], mr[RPW], sr[RPW], m40r[RPW];
  float rlx, rly, rlz, rhx, rhy, rhz;
#pragma unroll
  for (int r = 0; r < RPW; ++r) {
    float4 p = P4[wrow0 + r];
    pxr[r] = p.x; pyr[r] = p.y; pzr[r] = p.z; pwr[r] = p.w;
    if (r == 0) { rlx = rhx = p.x; rly = rhy = p.y; rlz = rhz = p.z; }
    else {
      rlx = fminf(rlx, p.x); rhx = fmaxf(rhx, p.x);
      rly = fminf(rly, p.y); rhy = fmaxf(rhy, p.y);
      rlz = fminf(rlz, p.z); rhz = fmaxf(rhz, p.z);
    }
  }
  const float cx = 0.5f * (rlx + rhx), cy = 0.5f * (rly + rhy), cz = 0.5f * (rlz + rhz);
  const float cw = fmaf(cx, cx, fmaf(cy, cy, cz * cz));  // |c|^2
  float rrad = 0.f;
#pragma unroll
  for (int r = 0; r < RPW; ++r) {
    float dx = pxr[r] - cx, dy = pyr[r] - cy, dz = pzr[r] - cz;
    rrad = fmaxf(rrad, fmaf(dx, dx, fmaf(dy, dy, dz * dz)));
  }
  rrad = fsqrt_(rrad);

  // ---- pass A: dense refine of the achievable bound ----
  // uc_j = hh_j - KKc*(|q_j - c| + rrad) <= term_rj for every row r.
  float ulbl = -INFINITY;
#pragma unroll 4
  for (int t = 0; t < NTL; ++t) {
    int j = t * 64 + lane;
    float4 q = Q4[j];
    float hh = fmaf(KKc, hsrc[j], HBc);
    float d2c = q.w + fmaf(q.x, cx, fmaf(q.y, cy, fmaf(q.z, cz, cw)));
    float d = fsqrt_(fmaxf(d2c, 0.f));
    ulbl = fmaxf(ulbl, fmaf(NKKc, d + rrad, hh));
  }
#pragma unroll
  for (int off = 32; off; off >>= 1) ulbl = fmaxf(ulbl, __shfl_xor(ulbl, off));
  const float ulb = ulbl;
  const float thr = ulb - WIN;

#pragma unroll
  for (int r = 0; r < RPW; ++r) { mr[r] = ulb; sr[r] = 0.f; m40r[r] = ulb + WIN; }

  auto inner8 = [&](float4 q, float hh) {
#pragma unroll
    for (int r = 0; r < RPW; ++r) {
      float dot = fmaf(pxr[r], q.x, fmaf(pyr[r], q.y, fmaf(pzr[r], q.z, q.w)));
      float d2  = pwr[r] + dot;
      float c   = fsqrt_(fmaxf(d2, 1e-12f));
      float u   = fmaf(NKKc, c, hh);
      if (__any(u > m40r[r])) {          // defer-max rescale (wave-uniform)
        float mn = fmaxf(mr[r], u);
        sr[r] *= fexp2(mr[r] - mn);
        mr[r] = mn; m40r[r] = mn + WIN;
      }
      sr[r] += fexp2(u - mr[r]);
    }
  };

  // ---- pass B: dense per-column keep test + ring compaction + batches ----
  int headq = 0, tailq = 0;
#pragma unroll 2
  for (int t = 0; t < NTL; ++t) {
    int j = t * 64 + lane;
    float4 q = Q4[j];
    float hh = fmaf(KKc, hsrc[j], HBc);
    float d2c = q.w + fmaf(q.x, cx, fmaf(q.y, cy, fmaf(q.z, cz, cw)));
    float d = fsqrt_(fmaxf(d2c, 0.f));
    float uhi = fmaf(NKKc, fmaxf(d - rrad, 0.f), hh); // >= any row's term
    bool keep = (uhi >= thr);
    unsigned long long k = __ballot(keep);
    if (k) {
      int my = __builtin_amdgcn_mbcnt_hi((unsigned)(k >> 32),
               __builtin_amdgcn_mbcnt_lo((unsigned)k, 0u));
      if (keep) {
        int slot = (tailq + my) & 127;   // ring: max 63 resident + 64 incoming
        ringQ[slot] = q;
        ringH[slot] = hh;
      }
      tailq += (int)__popcll(k);
      while (tailq - headq >= 64) {
        int slot = (headq + lane) & 127;
        float4 qq = ringQ[slot];
        float  hq = ringH[slot];
        headq += 64;
        inner8(qq, hq);
      }
    }
  }
  {
    int rem = tailq - headq;
    if (rem > 0) {
      int slot = (headq + lane) & 127;
      float4 qq = ringQ[slot];
      float  hq = ringH[slot];
      if (lane >= rem) { qq = make_float4(0.f, 0.f, 0.f, 0.f); hq = -INFINITY; }
      inner8(qq, hq);
    }
  }

  // ---- merge per-lane LSE states; write outputs ----
#pragma unroll
  for (int r = 0; r < RPW; ++r) {
    float m = mr[r], s = sr[r];
#pragma unroll
    for (int off = 32; off; off >>= 1) {
      float mo = __shfl_xor(m, off);
      float so = __shfl_xor(s, off);
      float mn = fmaxf(m, mo);
      s = s * fexp2(m - mn) + so * fexp2(mo - mn);
      m = mn;
    }
    if (lane == 0) {
      float val = NEL2c * (m + flog2(s));
      const int row = wrow0 + r;
      outp[row] = avg ? 0.5f * (oldp[row] + val) : val;
    }
  }
}

// loss = mean(f - px) + mean(g - py)
__global__ __launch_bounds__(256) void loss_kernel(
    const float* __restrict__ st, float* __restrict__ out)
{
  double acc = 0.0;
  for (int i = threadIdx.x; i < NP; i += 256)
    acc += (double)(st[i] - st[i + 2*NP]) + (double)(st[i + NP] - st[i + 3*NP]);
  __shared__ double red[4];
#pragma unroll
  for (int off = 32; off; off >>= 1) acc += __shfl_xor(acc, off);
  const int lane = threadIdx.x & 63, wave = threadIdx.x >> 6;
  if (lane == 0) red[wave] = acc;
  __syncthreads();
  if (threadIdx.x == 0)
    out[0] = (float)((red[0] + red[1] + red[2] + red[3]) * (1.0 / NP));
}

extern "C" void kernel_launch(void* const* d_in, const int* in_sizes, int n_in,
                              void* d_out, int out_size, void* d_ws, size_t ws_size,
                              hipStream_t stream)
{
  const float* x = (const float*)d_in[0];
  const float* y = (const float*)d_in[1];
  float* out = (float*)d_out;
  float* ws  = (float*)d_ws;

  float4* Xp = (float4*)ws;                    // NP float4 each
  float4* Xq = (float4*)(ws + 4 * NP);
  float4* Yp = (float4*)(ws + 8 * NP);
  float4* Yq = (float4*)(ws + 12 * NP);
  float* stA = ws + 16 * NP;                   // f,g,px,py (current)
  float* stB = stA + 4 * NP;                   // f,g,px,py (next)

  hipLaunchKernelGGL(sort_kernel, dim3(2), dim3(1024), 0, stream,
                     x, y, Xp, Xq, Yp, Yq, stA);

  float* cur = stA; float* nxt = stB;
  for (int it = 0; it <= 32; ++it) {
    const int avg = (it < 32) ? 1 : 0;   // 32 averaged steps + 1 extrapolation
    hipLaunchKernelGGL(softmin_pass, dim3(4 * NWG), dim3(64), 0, stream,
                       Xp, Yp, Xq, Yq, cur, nxt, avg);
    float* t = cur; cur = nxt; nxt = t;
  }

  hipLaunchKernelGGL(loss_kernel, dim3(1), dim3(256), 0, stream, cur, out);
}